// Round 4
// baseline (46.752 us; speedup 1.0000x reference)
//
#include <hip/hip_runtime.h>
#include <hip/hip_bf16.h>
#include <math.h>

#define HH 768
#define NB 8
#define LL 256
#define MM 128
#define NROW1 (NB*MM)        // 1024 dns rows
#define NROW2 (NB*LL)        // 2048 text rows
#define NROWS (NROW1+NROW2)  // 3072
#define NCB 12               // 768/64 column blocks

typedef __attribute__((ext_vector_type(8))) short  bf16x8;
typedef __attribute__((ext_vector_type(4))) float  f32x4;

static __device__ __forceinline__ unsigned int pkbf2(float a, float b) {
    __hip_bfloat162 h = __float22bfloat162_rn(make_float2(a, b));
    unsigned int u; __builtin_memcpy(&u, &h, 4); return u;
}

static __device__ __forceinline__ float fast_tanh(float x) {
    float e = __expf(2.0f * x);
    return 1.0f - 2.0f * __builtin_amdgcn_rcpf(e + 1.0f);
}

// ---------------------------------------------------------------------------
// One-shot fp32 -> bf16 conversion of all GEMM operands.
// Xb rows: [0,1024) = dns, [1024,3072) = text.  Wb: [Wd1 | Wt2].
// f4-region map: [0,196608) dns, [,589824) text, [,737280) Wd1, [,884736) Wt2.
// ---------------------------------------------------------------------------
__global__ __launch_bounds__(256) void prep_bf16(
    const float4* __restrict__ text, const float4* __restrict__ dns,
    const float4* __restrict__ Wd1, const float4* __restrict__ Wt2,
    uint2* __restrict__ Xb, uint2* __restrict__ Wb)
{
    const int i = blockIdx.x * 256 + threadIdx.x;   // grid exactly 884736 threads
    const float4* src; uint2* dst;
    if (i < 589824) {
        dst = Xb + i;
        src = (i < 196608) ? (dns + i) : (text + (i - 196608));
    } else {
        dst = Wb + (i - 589824);
        src = (i < 737280) ? (Wd1 + (i - 589824)) : (Wt2 + (i - 737280));
    }
    float4 v = *src;
    uint2 o; o.x = pkbf2(v.x, v.y); o.y = pkbf2(v.z, v.w);
    *dst = o;
}

// ---------------------------------------------------------------------------
// bf16-MFMA GEMM + tanh + dot (both score GEMMs).
// partial[row][cb] = sum_{o in colblock cb} tanh(X[row,:]·W[o,:]) * wvec[o]
// Tile 64x64, BK=64, 256 threads; wave w owns rows [w*16,w*16+16) x all 64
// cols so the 16-lane shuffle reduces the complete column sum.
// 1D grid 576 with XCD-chunked swizzle: XCD x gets row-blocks [6x,6x+6) x all
// 12 col-blocks -> per-XCD working set (A 576KB + W <=2.4MB) is L2-resident.
// ---------------------------------------------------------------------------
__global__ __launch_bounds__(256) void score_mfma(
    const unsigned short* __restrict__ Xb, const unsigned short* __restrict__ Wb,
    const float* __restrict__ wv1, const float* __restrict__ wv2,
    float* __restrict__ partial)
{
    __shared__ __align__(16) unsigned short As[64][72];
    __shared__ __align__(16) unsigned short Bs[64][72];

    const int t = threadIdx.x;
    const int tile = (blockIdx.x >> 3) + (blockIdx.x & 7) * 72;  // 576 = 8*72, bijective
    const int rb = tile / 12, cb = tile % 12;
    const int row0 = rb * 64, col0 = cb * 64;

    const unsigned short* X = Xb + (size_t)row0 * HH;
    const unsigned short* W; const float* wv;
    if (row0 < NROW1) { W = Wb;                    wv = wv1; }
    else              { W = Wb + (size_t)HH * HH;  wv = wv2; }

    const int sr = t >> 2;        // staging row 0..63
    const int c4 = t & 3;         // 16-elem k-subchunk
    const unsigned short* xp = X + (size_t)sr * HH + c4 * 16;
    const unsigned short* wp = W + (size_t)(col0 + sr) * HH + c4 * 16;

    const int l  = t & 63;
    const int w  = t >> 6;
    const int wr = w * 16;        // this wave's 16 output rows
    const int lc = l & 15;
    const int lk = (l >> 4) * 8;

    f32x4 acc[4] = {};
    uint4 rA0, rA1, rB0, rB1, nA0, nA1, nB0, nB1;

    auto STAGE = [&]() {
        *reinterpret_cast<uint4*>(&As[sr][c4 * 16    ]) = rA0;
        *reinterpret_cast<uint4*>(&As[sr][c4 * 16 + 8]) = rA1;
        *reinterpret_cast<uint4*>(&Bs[sr][c4 * 16    ]) = rB0;
        *reinterpret_cast<uint4*>(&Bs[sr][c4 * 16 + 8]) = rB1;
    };
    auto MFMA_TILE = [&]() {
        #pragma unroll
        for (int kk = 0; kk < 2; ++kk) {
            const int ko = kk * 32 + lk;
            bf16x8 a = *reinterpret_cast<const bf16x8*>(&As[wr + lc][ko]);
            #pragma unroll
            for (int n = 0; n < 4; ++n) {
                bf16x8 b = *reinterpret_cast<const bf16x8*>(&Bs[n*16 + lc][ko]);
                acc[n] = __builtin_amdgcn_mfma_f32_16x16x32_bf16(a, b, acc[n], 0, 0, 0);
            }
        }
    };

    // prologue loads (k0 = 0)
    rA0 = *(const uint4*)(xp);     rA1 = *(const uint4*)(xp + 8);
    rB0 = *(const uint4*)(wp);     rB1 = *(const uint4*)(wp + 8);

    #pragma unroll 1
    for (int k0 = 0; k0 < HH - 64; k0 += 64) {
        STAGE();
        __syncthreads();
        // prefetch next K-tile (latency hidden under MFMA phase)
        nA0 = *(const uint4*)(xp + k0 + 64);  nA1 = *(const uint4*)(xp + k0 + 72);
        nB0 = *(const uint4*)(wp + k0 + 64);  nB1 = *(const uint4*)(wp + k0 + 72);
        MFMA_TILE();
        __syncthreads();
        rA0 = nA0; rA1 = nA1; rB0 = nB0; rB1 = nB1;
    }
    STAGE();
    __syncthreads();
    MFMA_TILE();

    // epilogue: tanh * wvec over all 64 cols (4 frags), 16-lane reduce
    float wvn[4];
    #pragma unroll
    for (int n = 0; n < 4; ++n) wvn[n] = wv[col0 + n*16 + lc];
    #pragma unroll
    for (int i = 0; i < 4; ++i) {
        float s = 0.f;
        #pragma unroll
        for (int n = 0; n < 4; ++n) s += fast_tanh(acc[n][i]) * wvn[n];
        s += __shfl_xor(s, 1);
        s += __shfl_xor(s, 2);
        s += __shfl_xor(s, 4);
        s += __shfl_xor(s, 8);
        if (lc == 0)
            partial[(size_t)(row0 + wr + (l >> 4)*4 + i) * NCB + cb] = s;
    }
}

// ---------------------------------------------------------------------------
// Per (batch, h-chunk): reduce partials -> softmax (both) -> weighted sums.
// ---------------------------------------------------------------------------
__global__ __launch_bounds__(256) void finish_kernel(
    const float* __restrict__ text, const float* __restrict__ dns,
    const float* __restrict__ partial, float* __restrict__ vd, float* __restrict__ vt)
{
    const int b = blockIdx.x, hc = blockIdx.y;
    const int t = threadIdx.x;
    __shared__ float p1s[128], p2s[256], red[8], bd[256], bt[256];

    if (t < 128) {
        const float* pr = partial + (size_t)(b * MM + t) * NCB;
        float s = 0.f;
        #pragma unroll
        for (int c = 0; c < NCB; ++c) s += pr[c];
        p1s[t] = s;
    }
    {
        const float* pr = partial + (size_t)(NROW1 + b * LL + t) * NCB;
        float s = 0.f;
        #pragma unroll
        for (int c = 0; c < NCB; ++c) s += pr[c];
        p2s[t] = s;
    }
    __syncthreads();

    float x1 = (t < 128) ? p1s[t] : -1e30f;
    float m1 = x1;
    #pragma unroll
    for (int d = 1; d < 64; d <<= 1) m1 = fmaxf(m1, __shfl_xor(m1, d));
    if ((t & 63) == 0) red[t >> 6] = m1;
    float x2 = p2s[t];
    float m2 = x2;
    #pragma unroll
    for (int d = 1; d < 64; d <<= 1) m2 = fmaxf(m2, __shfl_xor(m2, d));
    if ((t & 63) == 0) red[4 + (t >> 6)] = m2;
    __syncthreads();
    m1 = fmaxf(fmaxf(red[0], red[1]), fmaxf(red[2], red[3]));
    m2 = fmaxf(fmaxf(red[4], red[5]), fmaxf(red[6], red[7]));

    float e1 = (t < 128) ? __expf(x1 - m1) : 0.f;
    float e2 = __expf(x2 - m2);
    __syncthreads();
    float s1 = e1, s2 = e2;
    #pragma unroll
    for (int d = 1; d < 64; d <<= 1) { s1 += __shfl_xor(s1, d); s2 += __shfl_xor(s2, d); }
    if ((t & 63) == 0) { red[t >> 6] = s1; red[4 + (t >> 6)] = s2; }
    __syncthreads();
    s1 = red[0] + red[1] + red[2] + red[3];
    s2 = red[4] + red[5] + red[6] + red[7];
    if (t < 128) p1s[t] = e1 / s1;
    p2s[t] = e2 / s2;
    __syncthreads();

    const int h = hc * 128 + (t & 127);
    const int slice = t >> 7;
    float sd = 0.f;
    #pragma unroll 4
    for (int m = slice * 64; m < slice * 64 + 64; ++m)
        sd = fmaf(p1s[m], dns[(size_t)(b * MM + m) * HH + h], sd);
    float st = 0.f;
    #pragma unroll 4
    for (int j = slice * 128; j < slice * 128 + 128; ++j)
        st = fmaf(p2s[j], text[(size_t)(b * LL + j) * HH + h], st);
    bd[t] = sd; bt[t] = st;
    __syncthreads();
    if (slice == 0) {
        vd[b * HH + h] = bd[t] + bd[t + 128];
        vt[b * HH + h] = bt[t] + bt[t + 128];
    }
}

// ---------------------------------------------------------------------------
// Broadcast: out[0..n) = att_text (vt over L), out[n..2n) = att_dns (vd).
// ---------------------------------------------------------------------------
__global__ __launch_bounds__(256) void bcast_kernel(
    const float* __restrict__ vt, const float* __restrict__ vd, float4* __restrict__ out)
{
    const int n4 = NB * LL * HH / 4;          // 393216 per output
    const int H4 = HH / 4;                    // 192
    const int LH4 = LL * H4;                  // 49152
    const float4* vt4 = reinterpret_cast<const float4*>(vt);
    const float4* vd4 = reinterpret_cast<const float4*>(vd);
    int i = blockIdx.x * blockDim.x + threadIdx.x;
    for (; i < 2 * n4; i += gridDim.x * blockDim.x) {
        const int which = (i >= n4);
        const int q = which ? (i - n4) : i;
        const int b = q / LH4;
        const int h4 = q % H4;
        const float4* src = which ? vd4 : vt4;
        out[i] = src[b * H4 + h4];
    }
}

extern "C" void kernel_launch(void* const* d_in, const int* in_sizes, int n_in,
                              void* d_out, int out_size, void* d_ws, size_t ws_size,
                              hipStream_t stream) {
    const float* text   = (const float*)d_in[0];   // (8,256,768)
    const float* dns    = (const float*)d_in[1];   // (8,128,768)
    const float* W_d1   = (const float*)d_in[4];   // (768,768)
    const float* w_att1 = (const float*)d_in[5];   // (1536,)
    const float* W_t2   = (const float*)d_in[9];   // (768,768)
    const float* w_att2 = (const float*)d_in[10];  // (1536,)

    float* ws      = (float*)d_ws;
    float* partial = ws;                                   // 3072*12 floats
    float* vd      = ws + 36864;                           // 6144
    float* vt      = ws + 43008;                           // 6144
    unsigned short* Xb = (unsigned short*)(ws + 49152);    // 2359296 bf16
    unsigned short* Wb = Xb + (size_t)NROWS * HH;          // 1179648 bf16
    float* out     = (float*)d_out;

    prep_bf16<<<3456, 256, 0, stream>>>(
        (const float4*)text, (const float4*)dns, (const float4*)W_d1,
        (const float4*)W_t2, (uint2*)Xb, (uint2*)Wb);
    score_mfma<<<576, 256, 0, stream>>>(
        Xb, Wb, w_att1 + HH, w_att2 + HH, partial);
    finish_kernel<<<dim3(NB, 6), 256, 0, stream>>>(text, dns, partial, vd, vt);
    bcast_kernel<<<3072, 256, 0, stream>>>(vt, vd, (float4*)out);
}

// Round 5
// 33.205 us; speedup vs baseline: 1.4080x; 1.4080x over previous
//
#include <hip/hip_runtime.h>
#include <hip/hip_bf16.h>
#include <math.h>

#define HH 768
#define NB 8
#define LL 256
#define MM 128
#define NROW1 (NB*MM)        // 1024 dns rows
#define NROW2 (NB*LL)        // 2048 text rows
#define NROWS (NROW1+NROW2)  // 3072
#define NCB 12               // 768/64 column blocks

typedef __attribute__((ext_vector_type(8))) short  bf16x8;
typedef __attribute__((ext_vector_type(4))) float  f32x4;

static __device__ __forceinline__ unsigned int pkbf2(float a, float b) {
    __hip_bfloat162 h = __float22bfloat162_rn(make_float2(a, b));
    unsigned int u; __builtin_memcpy(&u, &h, 4); return u;
}

static __device__ __forceinline__ float fast_tanh(float x) {
    float e = __expf(2.0f * x);
    return 1.0f - 2.0f * __builtin_amdgcn_rcpf(e + 1.0f);
}

// ---------------------------------------------------------------------------
// One-shot fp32 -> bf16 conversion of all GEMM operands.
// ---------------------------------------------------------------------------
__global__ __launch_bounds__(256) void prep_bf16(
    const float4* __restrict__ text, const float4* __restrict__ dns,
    const float4* __restrict__ Wd1, const float4* __restrict__ Wt2,
    uint2* __restrict__ Xb, uint2* __restrict__ Wb)
{
    const int i = blockIdx.x * 256 + threadIdx.x;   // 884736 threads exactly
    const float4* src; uint2* dst;
    if (i < 589824) {
        dst = Xb + i;
        src = (i < 196608) ? (dns + i) : (text + (i - 196608));
    } else {
        dst = Wb + (i - 589824);
        src = (i < 737280) ? (Wd1 + (i - 589824)) : (Wt2 + (i - 737280));
    }
    float4 v = *src;
    uint2 o; o.x = pkbf2(v.x, v.y); o.y = pkbf2(v.z, v.w);
    *dst = o;
}

// ---------------------------------------------------------------------------
// bf16-MFMA GEMM + tanh + dot (both score GEMMs). Proven round-3/4 structure.
// ---------------------------------------------------------------------------
__global__ __launch_bounds__(256) void score_mfma(
    const unsigned short* __restrict__ Xb, const unsigned short* __restrict__ Wb,
    const float* __restrict__ wv1, const float* __restrict__ wv2,
    float* __restrict__ partial)
{
    __shared__ __align__(16) unsigned short As[64][72];
    __shared__ __align__(16) unsigned short Bs[64][72];

    const int t = threadIdx.x;
    const int tile = (blockIdx.x >> 3) + (blockIdx.x & 7) * 72;  // 576 = 8*72
    const int rb = tile / 12, cb = tile % 12;
    const int row0 = rb * 64, col0 = cb * 64;

    const unsigned short* X = Xb + (size_t)row0 * HH;
    const unsigned short* W; const float* wv;
    if (row0 < NROW1) { W = Wb;                    wv = wv1; }
    else              { W = Wb + (size_t)HH * HH;  wv = wv2; }

    const int sr = t >> 2;
    const int c4 = t & 3;
    const unsigned short* xp = X + (size_t)sr * HH + c4 * 16;
    const unsigned short* wp = W + (size_t)(col0 + sr) * HH + c4 * 16;

    const int l  = t & 63;
    const int w  = t >> 6;
    const int wr = w * 16;
    const int lc = l & 15;
    const int lk = (l >> 4) * 8;

    f32x4 acc[4] = {};
    uint4 rA0, rA1, rB0, rB1, nA0, nA1, nB0, nB1;

    auto STAGE = [&]() {
        *reinterpret_cast<uint4*>(&As[sr][c4 * 16    ]) = rA0;
        *reinterpret_cast<uint4*>(&As[sr][c4 * 16 + 8]) = rA1;
        *reinterpret_cast<uint4*>(&Bs[sr][c4 * 16    ]) = rB0;
        *reinterpret_cast<uint4*>(&Bs[sr][c4 * 16 + 8]) = rB1;
    };
    auto MFMA_TILE = [&]() {
        #pragma unroll
        for (int kk = 0; kk < 2; ++kk) {
            const int ko = kk * 32 + lk;
            bf16x8 a = *reinterpret_cast<const bf16x8*>(&As[wr + lc][ko]);
            #pragma unroll
            for (int n = 0; n < 4; ++n) {
                bf16x8 b = *reinterpret_cast<const bf16x8*>(&Bs[n*16 + lc][ko]);
                acc[n] = __builtin_amdgcn_mfma_f32_16x16x32_bf16(a, b, acc[n], 0, 0, 0);
            }
        }
    };

    rA0 = *(const uint4*)(xp);     rA1 = *(const uint4*)(xp + 8);
    rB0 = *(const uint4*)(wp);     rB1 = *(const uint4*)(wp + 8);

    #pragma unroll 1
    for (int k0 = 0; k0 < HH - 64; k0 += 64) {
        STAGE();
        __syncthreads();
        nA0 = *(const uint4*)(xp + k0 + 64);  nA1 = *(const uint4*)(xp + k0 + 72);
        nB0 = *(const uint4*)(wp + k0 + 64);  nB1 = *(const uint4*)(wp + k0 + 72);
        MFMA_TILE();
        __syncthreads();
        rA0 = nA0; rA1 = nA1; rB0 = nB0; rB1 = nB1;
    }
    STAGE();
    __syncthreads();
    MFMA_TILE();

    float wvn[4];
    #pragma unroll
    for (int n = 0; n < 4; ++n) wvn[n] = wv[col0 + n*16 + lc];
    #pragma unroll
    for (int i = 0; i < 4; ++i) {
        float s = 0.f;
        #pragma unroll
        for (int n = 0; n < 4; ++n) s += fast_tanh(acc[n][i]) * wvn[n];
        s += __shfl_xor(s, 1);
        s += __shfl_xor(s, 2);
        s += __shfl_xor(s, 4);
        s += __shfl_xor(s, 8);
        if (lc == 0)
            partial[(size_t)(row0 + wr + (l >> 4)*4 + i) * NCB + cb] = s;
    }
}

// ---------------------------------------------------------------------------
// Reduce the 12 column-block partials per row, then per-batch softmax.
// (round-1 proven code)
// ---------------------------------------------------------------------------
__global__ __launch_bounds__(256) void softmax_kernel(
    const float* __restrict__ partial, float* __restrict__ p1, float* __restrict__ p2)
{
    const int which = blockIdx.x >> 3;
    const int b = blockIdx.x & 7;
    const int n = which ? 256 : 128;
    const int row_base = which ? (NROW1 + b * 256) : (b * 128);
    float* dst = which ? (p2 + b * 256) : (p1 + b * 128);

    const int t = threadIdx.x;
    float v = -INFINITY;
    if (t < n) {
        float vv = 0.f;
        const float* pr = partial + (size_t)(row_base + t) * NCB;
        #pragma unroll
        for (int c = 0; c < NCB; ++c) vv += pr[c];
        v = vv;
    }

    __shared__ float sbuf[4];
    float m = v;
    #pragma unroll
    for (int d = 1; d < 64; d <<= 1) m = fmaxf(m, __shfl_xor(m, d));
    if ((t & 63) == 0) sbuf[t >> 6] = m;
    __syncthreads();
    m = fmaxf(fmaxf(sbuf[0], sbuf[1]), fmaxf(sbuf[2], sbuf[3]));
    __syncthreads();

    float e = (t < n) ? __expf(v - m) : 0.f;
    float s = e;
    #pragma unroll
    for (int d = 1; d < 64; d <<= 1) s += __shfl_xor(s, d);
    if ((t & 63) == 0) sbuf[t >> 6] = s;
    __syncthreads();
    s = sbuf[0] + sbuf[1] + sbuf[2] + sbuf[3];

    if (t < n) dst[t] = e / s;
}

// ---------------------------------------------------------------------------
// Weighted sums, split 8 ways over the reduction axis for CU-level BW.
// grid (8 b, 6 hc, 8 rs), 256 thr = 128 h x 2 row-subslices.
// pvt[rs][b][h] = sum over this slice's 32 text rows; pvd likewise (16 dns).
// ---------------------------------------------------------------------------
__global__ __launch_bounds__(256) void wsum_kernel(
    const float* __restrict__ text, const float* __restrict__ dns,
    const float* __restrict__ p1, const float* __restrict__ p2,
    float* __restrict__ pvt, float* __restrict__ pvd)
{
    const int b = blockIdx.x, hc = blockIdx.y, rs = blockIdx.z;
    const int t = threadIdx.x;
    const int h = hc * 128 + (t & 127);
    const int sub = t >> 7;

    const int jr0 = rs * 32 + sub * 16;          // 16 text rows
    float st = 0.f;
    #pragma unroll
    for (int r = 0; r < 16; ++r)
        st = fmaf(p2[b * LL + jr0 + r], text[(size_t)(b * LL + jr0 + r) * HH + h], st);

    const int mr0 = rs * 16 + sub * 8;           // 8 dns rows
    float sd = 0.f;
    #pragma unroll
    for (int r = 0; r < 8; ++r)
        sd = fmaf(p1[b * MM + mr0 + r], dns[(size_t)(b * MM + mr0 + r) * HH + h], sd);

    __shared__ float bt[256], bd[256];
    bt[t] = st; bd[t] = sd;
    __syncthreads();
    if (sub == 0) {
        pvt[(size_t)(rs * NB + b) * HH + h] = bt[t] + bt[t + 128];
        pvd[(size_t)(rs * NB + b) * HH + h] = bd[t] + bd[t + 128];
    }
}

// ---------------------------------------------------------------------------
// Sum the 8 partials (L2-hot) and broadcast-write both outputs.
// 256 blocks = 8 b x 32 L-chunks (8 rows each).
// ---------------------------------------------------------------------------
__global__ __launch_bounds__(256) void bcast_reduce(
    const float4* __restrict__ pvt4, const float4* __restrict__ pvd4,
    float4* __restrict__ out)
{
    const int b = blockIdx.x >> 5;
    const int l0 = (blockIdx.x & 31) * 8;
    const int t = threadIdx.x;
    const int H4 = HH / 4;                       // 192
    const int n4out = NB * LL * H4;              // 393216

    __shared__ float4 svt[192], svd[192];
    if (t < 192) {
        float4 a = make_float4(0.f, 0.f, 0.f, 0.f);
        float4 c = make_float4(0.f, 0.f, 0.f, 0.f);
        #pragma unroll
        for (int s = 0; s < 8; ++s) {
            float4 u = pvt4[(size_t)(s * NB + b) * H4 + t];
            float4 v = pvd4[(size_t)(s * NB + b) * H4 + t];
            a.x += u.x; a.y += u.y; a.z += u.z; a.w += u.w;
            c.x += v.x; c.y += v.y; c.z += v.z; c.w += v.w;
        }
        svt[t] = a; svd[t] = c;
    }
    __syncthreads();

    #pragma unroll
    for (int i = t; i < 1536; i += 256) {        // 8 rows x 192 f4
        const int row = i / 192, h4 = i % 192;
        const int l = l0 + row;
        out[(size_t)(b * LL + l) * H4 + h4] = svt[h4];
        out[n4out + (size_t)(b * LL + l) * H4 + h4] = svd[h4];
    }
}

extern "C" void kernel_launch(void* const* d_in, const int* in_sizes, int n_in,
                              void* d_out, int out_size, void* d_ws, size_t ws_size,
                              hipStream_t stream) {
    const float* text   = (const float*)d_in[0];   // (8,256,768)
    const float* dns    = (const float*)d_in[1];   // (8,128,768)
    const float* W_d1   = (const float*)d_in[4];   // (768,768)
    const float* w_att1 = (const float*)d_in[5];   // (1536,)
    const float* W_t2   = (const float*)d_in[9];   // (768,768)
    const float* w_att2 = (const float*)d_in[10];  // (1536,)

    float* ws      = (float*)d_ws;
    float* partial = ws;                                   // 36864 f
    float* p1      = ws + 36864;                           // 1024
    float* p2      = ws + 37888;                           // 2048
    float* pvt     = ws + 39936;                           // 49152
    float* pvd     = ws + 89088;                           // 49152
    unsigned short* Xb = (unsigned short*)(ws + 138240);   // 2359296 bf16
    unsigned short* Wb = Xb + (size_t)NROWS * HH;          // 1179648 bf16
    float* out     = (float*)d_out;

    prep_bf16<<<3456, 256, 0, stream>>>(
        (const float4*)text, (const float4*)dns, (const float4*)W_d1,
        (const float4*)W_t2, (uint2*)Xb, (uint2*)Wb);
    score_mfma<<<576, 256, 0, stream>>>(
        Xb, Wb, w_att1 + HH, w_att2 + HH, partial);
    softmax_kernel<<<16, 256, 0, stream>>>(partial, p1, p2);
    wsum_kernel<<<dim3(NB, 6, 8), 256, 0, stream>>>(text, dns, p1, p2, pvt, pvd);
    bcast_reduce<<<256, 256, 0, stream>>>(
        (const float4*)pvt, (const float4*)pvd, (float4*)out);
}